// Round 19
// baseline (307.818 us; speedup 1.0000x reference)
//
#include <hip/hip_runtime.h>
#include <hip/hip_bf16.h>
#include <stdint.h>

#define NN 8192
#define GG 512
#define HH 512
#define LL 64
#define TOPK 9                 // K+1 = 9 (incl. self, self weight zeroed)
#define NEDGE (NN*TOPK)        // 73728 directed edges
#define NNZ (2*NEDGE)          // 147456 CSR entries after symmetrization
#define GRES 32                // spatial grid resolution (cell = 1/32)
#define NCELL (GRES*GRES)
#define LPAD 68                // LDS row pad: 34 dwords == 2 mod 32

typedef unsigned long long u64;
typedef unsigned int u32;
typedef unsigned short u16;

using bf16x8 = __attribute__((ext_vector_type(8))) short;
using f32x4  = __attribute__((ext_vector_type(4))) float;

struct InPtrs { const void* p[12]; };

__device__ __forceinline__ float bf2f(u16 u) { return __uint_as_float(((u32)u) << 16); }
__device__ __forceinline__ u16 f2bf(float f) {
  u32 x = __float_as_uint(f);
  u32 r = x + 0x7fffu + ((x >> 16) & 1u);   // RNE
  return (u16)(r >> 16);
}

// ---------------- inline dtype detection (wave 0 samples 64 u16s of coords) ----------------
__device__ __forceinline__ int detect_isbf(const void* coords_raw, int tid, int* sh) {
  if (tid < 64) {
    float v = bf2f(((const u16*)coords_raw)[tid]);
    bool bad = !(v >= -0.01f && v <= 1.02f);
    u64 bb = __ballot(bad);
    if (tid == 0) *sh = (bb == 0ULL) ? 1 : 0;
  }
  __syncthreads();
  return *sh;
}

// ---------------- convert small tensors + flag + zero deg/cnt + sq (from raw coords) ----------------
__global__ void k_conv_small(InPtrs in, int* __restrict__ flag,
                             float* __restrict__ f32blk, u16* __restrict__ bfblk,
                             float* __restrict__ deg, int* __restrict__ cnt,
                             float* __restrict__ sq) {
  __shared__ int sh;
  const int cnts[11] = {16384, 262144, 512, 1024, 512, 262144, 512, 262144, 512, 32768, 64};
  const int kind[11] = {0, 1, 0, 0, 0, 1, 0, 1, 0, 1, 0};
  const int doff[11] = {0, 0, 16384, 16896, 17920, 262144, 18432, 524288, 18944, 786432, 19456};
  const int TOTAL = 838720;
  int tid = threadIdx.x;
  int isbf = detect_isbf(in.p[1], tid, &sh);
  int gtid = blockIdx.x * blockDim.x + tid;
  if (gtid == 0) *flag = isbf;
  if (gtid < NN) {
    deg[gtid] = 0.0f;
    float x, y;
    if (isbf) { x = bf2f(((const u16*)in.p[1])[2 * gtid]); y = bf2f(((const u16*)in.p[1])[2 * gtid + 1]); }
    else      { x = ((const float*)in.p[1])[2 * gtid];     y = ((const float*)in.p[1])[2 * gtid + 1]; }
    sq[gtid] = __fadd_rn(__fmul_rn(x, x), __fmul_rn(y, y));
  } else if (gtid < 2 * NN) {
    cnt[gtid - NN] = 0;
  }
  for (int e = gtid; e < TOTAL; e += gridDim.x * blockDim.x) {
    int base = 0;
#pragma unroll
    for (int s = 0; s < 11; ++s) {
      if (e < base + cnts[s]) {
        int loc = e - base;
        const void* src = in.p[s + 1];
        float fv = isbf ? bf2f(((const u16*)src)[loc]) : ((const float*)src)[loc];
        if (kind[s] == 0) f32blk[doff[s] + loc] = fv;
        else bfblk[doff[s] + loc] = isbf ? ((const u16*)src)[loc] : f2bf(fv);
        break;
      }
      base += cnts[s];
    }
  }
}

// ---------------- gene -> bf16 ONLY in the fp32-input world ----------------
__global__ void k_conv_gene(const void* __restrict__ src, const void* __restrict__ coords_raw,
                            u32* __restrict__ geneB) {
  __shared__ int sh;
  const int TOTAL = NN * GG / 2;
  int isbf = detect_isbf(coords_raw, threadIdx.x, &sh);
  if (isbf) return;
  for (int e = blockIdx.x * blockDim.x + threadIdx.x; e < TOTAL; e += gridDim.x * blockDim.x) {
    float2 f = ((const float2*)src)[e];
    geneB[e] = (u32)f2bf(f.x) | ((u32)f2bf(f.y) << 16);
  }
}

__device__ __forceinline__ int cell_of(float v) {
  int c = (int)(v * (float)GRES);
  return c < 0 ? 0 : (c > GRES - 1 ? GRES - 1 : c);
}

// ---------------- grid histogram + scan (single block, LDS histogram) ----------------
__global__ __launch_bounds__(1024) void k_grid_scan(const float* __restrict__ coords,
                                                    int* __restrict__ gstart, int* __restrict__ gcur) {
  __shared__ int hist[NCELL];
  int t = threadIdx.x;
  hist[t] = 0;
  __syncthreads();
#pragma unroll
  for (int q = 0; q < 8; ++q) {
    int i = t + 1024 * q;
    int cx = cell_of(coords[2 * i]), cy = cell_of(coords[2 * i + 1]);
    atomicAdd(&hist[cy * GRES + cx], 1);
  }
  __syncthreads();
  int v = hist[t];
  __syncthreads();
  __shared__ int part[NCELL];
  part[t] = v;
  __syncthreads();
  for (int o = 1; o < NCELL; o <<= 1) {
    int add = 0;
    if (t >= o) add = part[t - o];
    __syncthreads();
    part[t] += add;
    __syncthreads();
  }
  int excl = part[t] - v;
  gstart[t] = excl;
  gcur[t] = excl;
  if (t == NCELL - 1) gstart[NCELL] = part[t];
}

__global__ void k_grid_fill(const float* __restrict__ coords, const float* __restrict__ sq,
                            int* __restrict__ gcur, float4* __restrict__ pts) {
  int i = blockIdx.x * blockDim.x + threadIdx.x;
  if (i < NN) {
    float x = coords[2*i], y = coords[2*i+1];
    int cx = cell_of(x), cy = cell_of(y);
    int p = atomicAdd(&gcur[cy * GRES + cx], 1);
    pts[p] = make_float4(x, y, sq[i], __int_as_float(i));
  }
}

// ---------------- KNN top-9 via spatial grid (exact; inline full-scan fallback) ----------------
__global__ __launch_bounds__(256) void k_knn_grid(const float4* __restrict__ pts,
                                                  const int* __restrict__ gstart,
                                                  const float* __restrict__ coords,
                                                  const float* __restrict__ sq,
                                                  int* __restrict__ eidx, float* __restrict__ ew) {
  const int w = threadIdx.x >> 6, lane = threadIdx.x & 63;
  const int i = blockIdx.x * 4 + w;
  const float qx = coords[2*i], qy = coords[2*i+1];
  const float sqi = sq[i];
  const int cx = cell_of(qx), cy = cell_of(qy);
  const int x0 = max(cx - 2, 0), x1 = min(cx + 2, GRES - 1);
  const int y0 = max(cy - 2, 0), y1 = min(cy + 2, GRES - 1);

  u64 a0 = ~0ULL, a1 = ~0ULL, a2 = ~0ULL, a3 = ~0ULL, a4 = ~0ULL,
      a5 = ~0ULL, a6 = ~0ULL, a7 = ~0ULL, a8 = ~0ULL;

#define KSTEP(A) { u64 t_ = A; bool p_ = x < t_; A = p_ ? x : t_; x = p_ ? t_ : x; }
  for (int yy = y0; yy <= y1; ++yy) {
    int sbeg = gstart[yy * GRES + x0];
    int send = gstart[yy * GRES + x1 + 1];
    for (int p = sbeg + lane; p < send; p += 64) {
      float4 pt = pts[p];
      float dot = __fmaf_rn(qy, pt.y, __fmul_rn(qx, pt.x));
      float d2  = __fsub_rn(__fadd_rn(sqi, pt.z), __fmul_rn(2.0f, dot));
      float d   = __fsqrt_rn(fmaxf(d2, 0.0f));
      u64 x = ((u64)__float_as_uint(d) << 32) | (u32)__float_as_int(pt.w);
      KSTEP(a0) KSTEP(a1) KSTEP(a2) KSTEP(a3) KSTEP(a4)
      KSTEP(a5) KSTEP(a6) KSTEP(a7) KSTEP(a8)
    }
  }

  u64 g9 = ~0ULL;
  for (int r = 0; r < TOPK; ++r) {
    u64 g = a0;
#pragma unroll
    for (int o = 32; o > 0; o >>= 1) {
      u64 other = __shfl_xor(g, o, 64);
      if (other < g) g = other;
    }
    bool own = (a0 == g);
    a0 = own ? a1 : a0;  a1 = own ? a2 : a1;  a2 = own ? a3 : a2;
    a3 = own ? a4 : a3;  a4 = own ? a5 : a4;  a5 = own ? a6 : a5;
    a6 = own ? a7 : a6;  a7 = own ? a8 : a7;  a8 = own ? ~0ULL : a8;
    g9 = g;
    if (lane == 0) {
      u32 dbits = (u32)(g >> 32);
      int j = (int)(g & 0xffffffffu);
      float d = __uint_as_float(dbits);
      float wgt = (j == i) ? 0.0f : expf(__fdiv_rn(-__fmul_rn(d, d), 2.0f));
      eidx[i * TOPK + r] = j;
      ew[i * TOPK + r] = wgt;
    }
  }

  float d9 = __uint_as_float((u32)(g9 >> 32));
  if (!(d9 < 0.0624f)) {
    a0 = a1 = a2 = a3 = a4 = a5 = a6 = a7 = a8 = ~0ULL;
    const float2* c2 = (const float2*)coords;
    for (int c = 0; c < 128; ++c) {
      int j = c * 64 + lane;
      float2 cjf = c2[j];
      float dot = __fmaf_rn(qy, cjf.y, __fmul_rn(qx, cjf.x));
      float d2  = __fsub_rn(__fadd_rn(sqi, sq[j]), __fmul_rn(2.0f, dot));
      float d   = __fsqrt_rn(fmaxf(d2, 0.0f));
      u64 x = ((u64)__float_as_uint(d) << 32) | (u32)j;
      KSTEP(a0) KSTEP(a1) KSTEP(a2) KSTEP(a3) KSTEP(a4)
      KSTEP(a5) KSTEP(a6) KSTEP(a7) KSTEP(a8)
    }
    for (int r = 0; r < TOPK; ++r) {
      u64 g = a0;
#pragma unroll
      for (int o = 32; o > 0; o >>= 1) {
        u64 other = __shfl_xor(g, o, 64);
        if (other < g) g = other;
      }
      bool own = (a0 == g);
      a0 = own ? a1 : a0;  a1 = own ? a2 : a1;  a2 = own ? a3 : a2;
      a3 = own ? a4 : a3;  a4 = own ? a5 : a4;  a5 = own ? a6 : a5;
      a6 = own ? a7 : a6;  a7 = own ? a8 : a7;  a8 = own ? ~0ULL : a8;
      if (lane == 0) {
        u32 dbits = (u32)(g >> 32);
        int j = (int)(g & 0xffffffffu);
        float d = __uint_as_float(dbits);
        float wgt = (j == i) ? 0.0f : expf(__fdiv_rn(-__fmul_rn(d, d), 2.0f));
        eidx[i * TOPK + r] = j;
        ew[i * TOPK + r] = wgt;
      }
    }
  }
#undef KSTEP
}

// ---------------- fused degree + count ----------------
__global__ void k_degcnt(const int* __restrict__ eidx, const float* __restrict__ ew,
                         float* __restrict__ deg, int* __restrict__ cnt) {
  int t = blockIdx.x * blockDim.x + threadIdx.x;
  if (t >= NEDGE) return;
  int i = t / TOPK;
  int j = eidx[t] & (NN - 1);
  float h = 0.5f * ew[t];
  atomicAdd(&deg[i], h);
  atomicAdd(&deg[j], h);
  atomicAdd(&cnt[i], 1);
  atomicAdd(&cnt[j], 1);
}

// ---------------- CSR scan (+ dis from deg) ----------------
__global__ __launch_bounds__(1024) void k_scan(const int* __restrict__ cnt,
                                               const float* __restrict__ deg,
                                               int* __restrict__ rs, int* __restrict__ cur,
                                               float* __restrict__ dis) {
  __shared__ int part[1024];
  int t = threadIdx.x;
  int base = t * 8;
  int loc[8]; int s = 0;
#pragma unroll
  for (int q = 0; q < 8; ++q) { loc[q] = s; s += cnt[base + q]; }
  part[t] = s;
  __syncthreads();
  for (int o = 1; o < 1024; o <<= 1) {
    int v = 0;
    if (t >= o) v = part[t - o];
    __syncthreads();
    part[t] += v;
    __syncthreads();
  }
  int excl = (t == 0) ? 0 : part[t - 1];
#pragma unroll
  for (int q = 0; q < 8; ++q) {
    int val = excl + loc[q];
    rs[base + q] = val;
    cur[base + q] = val;
    dis[base + q] = 1.0f / sqrtf(deg[base + q] + 1e-8f);
  }
  if (t == 1023) rs[NN] = excl + s;
}

__global__ void k_fill(const int* __restrict__ eidx, const float* __restrict__ ew,
                       int* __restrict__ cur, int* __restrict__ ccol, float* __restrict__ cw) {
  int t = blockIdx.x * blockDim.x + threadIdx.x;
  if (t >= NEDGE) return;
  int i = t / TOPK;
  int j = eidx[t] & (NN - 1);
  float h = 0.5f * ew[t];
  int s1 = atomicAdd(&cur[i], 1); ccol[s1] = j; cw[s1] = h;
  int s2 = atomicAdd(&cur[j], 1); ccol[s2] = i; cw[s2] = h;
}

// ---------------- agg = A_norm @ h (bf16 in/out; NT packed stores) ----------------
__global__ __launch_bounds__(256) void k_agg(const int* __restrict__ rs, const int* __restrict__ ccol,
                                             const float* __restrict__ cw, const float* __restrict__ dis,
                                             const u16* __restrict__ h, u16* __restrict__ agg) {
  int i = blockIdx.x, t = threadIdx.x;
  int b = rs[i], e = rs[i + 1];
  float di = dis[i];
  float s0 = 0.f, s1 = 0.f;
  for (int q = b; q < e; ++q) {
    int c = ccol[q];
    float w = cw[q] * dis[c];
    u32 p = *(const u32*)(h + (size_t)c * HH + 2 * t);
    s0 = fmaf(w, bf2f((u16)(p & 0xffff)), s0);
    s1 = fmaf(w, bf2f((u16)(p >> 16)), s1);
  }
  u32 packed = (u32)f2bf(di * s0) | ((u32)f2bf(di * s1) << 16);
  __builtin_nontemporal_store(packed, (u32*)(agg + (size_t)i * HH + 2 * t));
}

// ---------------- MFMA bf16 GEMM, BM=128: C = A[M,512]*W[C,512]^T (NT stores) ----------------
template <int MODE>
__global__ __launch_bounds__(256) void k_mgemm(const void* __restrict__ Araw, const u16* __restrict__ Aconv,
                                               const u16* __restrict__ W,
                                               const float* __restrict__ bias,
                                               const float* __restrict__ coords,
                                               const float* __restrict__ Wc1, const float* __restrict__ bc1,
                                               const int* __restrict__ flag,
                                               void* __restrict__ outp, int ldc) {
  __shared__ u16 As[128][LPAD];
  __shared__ u16 Bs[64][LPAD];
  const int tid = threadIdx.x, lane = tid & 63, w = tid >> 6;
  const int quad = lane >> 4, l16 = lane & 15;
  const int row0 = blockIdx.x * 128, col0 = blockIdx.y * 64;

  int flg = *flag;
  const u16* A = (MODE == 0) ? ((flg ? (const u16*)Araw : Aconv)) : Aconv;

  f32x4 acc[2][4];
#pragma unroll
  for (int mr = 0; mr < 2; ++mr)
#pragma unroll
    for (int n = 0; n < 4; ++n) acc[mr][n] = (f32x4){0.f, 0.f, 0.f, 0.f};

  const int r_ld = tid >> 3, c8_ld = (tid & 7) * 8;

  for (int kk = 0; kk < 512; kk += 64) {
    uint4 av[4]; uint4 bv[2];
#pragma unroll
    for (int q = 0; q < 4; ++q)
      av[q] = *(const uint4*)(A + (size_t)(row0 + r_ld + 32 * q) * 512 + kk + c8_ld);
#pragma unroll
    for (int q = 0; q < 2; ++q)
      bv[q] = *(const uint4*)(W + (size_t)(col0 + r_ld + 32 * q) * 512 + kk + c8_ld);
    __syncthreads();
#pragma unroll
    for (int q = 0; q < 4; ++q)
      *(uint4*)(&As[r_ld + 32 * q][c8_ld]) = av[q];
#pragma unroll
    for (int q = 0; q < 2; ++q)
      *(uint4*)(&Bs[r_ld + 32 * q][c8_ld]) = bv[q];
    __syncthreads();
#pragma unroll
    for (int kc = 0; kc < 2; ++kc) {
      bf16x8 af[2], bfr[4];
#pragma unroll
      for (int mr = 0; mr < 2; ++mr)
        af[mr] = *(const bf16x8*)(&As[w * 32 + mr * 16 + l16][kc * 32 + quad * 8]);
#pragma unroll
      for (int n = 0; n < 4; ++n)
        bfr[n] = *(const bf16x8*)(&Bs[n * 16 + l16][kc * 32 + quad * 8]);
#pragma unroll
      for (int mr = 0; mr < 2; ++mr)
#pragma unroll
        for (int n = 0; n < 4; ++n)
          acc[mr][n] = __builtin_amdgcn_mfma_f32_16x16x32_bf16(af[mr], bfr[n], acc[mr][n], 0, 0, 0);
    }
  }

#pragma unroll
  for (int mr = 0; mr < 2; ++mr) {
    int rbase = row0 + w * 32 + mr * 16 + quad * 4;
    float cx[4], cy[4];
    if (MODE == 0) {
#pragma unroll
      for (int reg = 0; reg < 4; ++reg) { cx[reg] = coords[2 * (rbase + reg)]; cy[reg] = coords[2 * (rbase + reg) + 1]; }
    }
#pragma unroll
    for (int n = 0; n < 4; ++n) {
      int cg = col0 + n * 16 + l16;
      float bval = bias[cg];
      float wc0 = 0.f, wc1 = 0.f, bcv = 0.f;
      if (MODE == 0) { wc0 = Wc1[2 * cg]; wc1 = Wc1[2 * cg + 1]; bcv = bc1[cg]; }
#pragma unroll
      for (int reg = 0; reg < 4; ++reg) {
        int rg = rbase + reg;
        float v = acc[mr][n][reg] + bval;
        if (MODE == 0) {
          float hc = cx[reg] * wc0 + cy[reg] * wc1 + bcv;
          v = fmaxf(v, 0.f) + fmaxf(hc, 0.f);
          __builtin_nontemporal_store(f2bf(v), (u16*)outp + (size_t)rg * ldc + cg);
        } else {
          if (flg) __builtin_nontemporal_store(f2bf(v), (u16*)outp + (size_t)rg * ldc + cg);
          else     ((float*)outp)[(size_t)rg * ldc + cg] = v;
        }
      }
    }
  }
}

// ---------------- FUSED GEMM2+3 (dual-stream, BM=128, 2 blocks/CU cap, NT stores) ----------------
__global__ __launch_bounds__(256) void k_mgemm23(const u16* __restrict__ A1, const u16* __restrict__ W1,
                                                 const float* __restrict__ b1,
                                                 const u16* __restrict__ A2, const u16* __restrict__ W2,
                                                 const float* __restrict__ b2,
                                                 u16* __restrict__ outp) {
  __shared__ u16 As1[128][LPAD];
  __shared__ u16 As2[128][LPAD];
  __shared__ u16 Bs1[80][LPAD];   // rows 0..63 used; extra rows cap occupancy at 2 blocks/CU
  __shared__ u16 Bs2[80][LPAD];
  const int tid = threadIdx.x, lane = tid & 63, w = tid >> 6;
  const int quad = lane >> 4, l16 = lane & 15;
  const int row0 = blockIdx.x * 128, col0 = blockIdx.y * 64;

  f32x4 acc1[2][4], acc2[2][4];
#pragma unroll
  for (int mr = 0; mr < 2; ++mr)
#pragma unroll
    for (int n = 0; n < 4; ++n) {
      acc1[mr][n] = (f32x4){0.f, 0.f, 0.f, 0.f};
      acc2[mr][n] = (f32x4){0.f, 0.f, 0.f, 0.f};
    }

  const int r_ld = tid >> 3, c8_ld = (tid & 7) * 8;

  for (int kk = 0; kk < 512; kk += 64) {
    uint4 av1[4], av2[4], bv1[2], bv2[2];
#pragma unroll
    for (int q = 0; q < 4; ++q) {
      av1[q] = *(const uint4*)(A1 + (size_t)(row0 + r_ld + 32 * q) * 512 + kk + c8_ld);
      av2[q] = *(const uint4*)(A2 + (size_t)(row0 + r_ld + 32 * q) * 512 + kk + c8_ld);
    }
#pragma unroll
    for (int q = 0; q < 2; ++q) {
      bv1[q] = *(const uint4*)(W1 + (size_t)(col0 + r_ld + 32 * q) * 512 + kk + c8_ld);
      bv2[q] = *(const uint4*)(W2 + (size_t)(col0 + r_ld + 32 * q) * 512 + kk + c8_ld);
    }
    __syncthreads();
#pragma unroll
    for (int q = 0; q < 4; ++q) {
      *(uint4*)(&As1[r_ld + 32 * q][c8_ld]) = av1[q];
      *(uint4*)(&As2[r_ld + 32 * q][c8_ld]) = av2[q];
    }
#pragma unroll
    for (int q = 0; q < 2; ++q) {
      *(uint4*)(&Bs1[r_ld + 32 * q][c8_ld]) = bv1[q];
      *(uint4*)(&Bs2[r_ld + 32 * q][c8_ld]) = bv2[q];
    }
    __syncthreads();
#pragma unroll
    for (int kc = 0; kc < 2; ++kc) {
      bf16x8 af1[2], af2[2], bf1[4], bf2[4];
#pragma unroll
      for (int mr = 0; mr < 2; ++mr) {
        af1[mr] = *(const bf16x8*)(&As1[w * 32 + mr * 16 + l16][kc * 32 + quad * 8]);
        af2[mr] = *(const bf16x8*)(&As2[w * 32 + mr * 16 + l16][kc * 32 + quad * 8]);
      }
#pragma unroll
      for (int n = 0; n < 4; ++n) {
        bf1[n] = *(const bf16x8*)(&Bs1[n * 16 + l16][kc * 32 + quad * 8]);
        bf2[n] = *(const bf16x8*)(&Bs2[n * 16 + l16][kc * 32 + quad * 8]);
      }
#pragma unroll
      for (int mr = 0; mr < 2; ++mr)
#pragma unroll
        for (int n = 0; n < 4; ++n) {
          acc1[mr][n] = __builtin_amdgcn_mfma_f32_16x16x32_bf16(af1[mr], bf1[n], acc1[mr][n], 0, 0, 0);
          acc2[mr][n] = __builtin_amdgcn_mfma_f32_16x16x32_bf16(af2[mr], bf2[n], acc2[mr][n], 0, 0, 0);
        }
    }
  }

#pragma unroll
  for (int mr = 0; mr < 2; ++mr) {
    int rbase = row0 + w * 32 + mr * 16 + quad * 4;
#pragma unroll
    for (int n = 0; n < 4; ++n) {
      int cg = col0 + n * 16 + l16;
      float bv1 = b1[cg], bv2 = b2[cg];
#pragma unroll
      for (int reg = 0; reg < 4; ++reg) {
        int rg = rbase + reg;
        float msg  = fmaxf(acc1[mr][n][reg] + bv1, 0.f);
        float self = fmaxf(acc2[mr][n][reg] + bv2, 0.f);
        __builtin_nontemporal_store(f2bf(fmaxf(msg + self, 0.f)), outp + (size_t)rg * 512 + cg);
      }
    }
  }
}

extern "C" void kernel_launch(void* const* d_in, const int* in_sizes, int n_in,
                              void* d_out, int out_size, void* d_ws, size_t ws_size,
                              hipStream_t stream) {
  float* ws = (float*)d_ws;
  size_t off = 0;
  auto alloc = [&](size_t n) { size_t o = off; off += (n + 15) & ~(size_t)15; return o; };

  const size_t PLANE = (size_t)NN * HH / 2;

  size_t o_flag  = alloc(16);
  size_t o_f32   = alloc(19520);
  size_t o_bfw   = alloc(409600);
  size_t o_geneB = alloc(PLANE);
  size_t o_Hb    = alloc(PLANE);
  size_t o_Mb    = alloc(PLANE);
  size_t o_sq    = alloc(NN);
  size_t o_deg   = alloc(NN);
  size_t o_dis   = alloc(NN);
  size_t o_cnt   = alloc(NN);
  size_t o_rs    = alloc(NN + 16);
  size_t o_cur   = alloc(NN);
  size_t o_eidx  = alloc(NEDGE);
  size_t o_ew    = alloc(NEDGE);
  size_t o_ccol  = alloc(NNZ);
  size_t o_cw    = alloc(NNZ);
  size_t o_pts   = alloc(NN * 4);
  size_t o_gsta  = alloc(NCELL + 16);
  size_t o_gcur  = alloc(NCELL);
  (void)ws_size;

  int*   flag    = (int*)(ws + o_flag);
  float* f32blk  = ws + o_f32;
  float* coordsF = f32blk + 0;
  float* bg1     = f32blk + 16384;
  float* Wc1f    = f32blk + 16896;
  float* bc1f    = f32blk + 17920;
  float* bmsg    = f32blk + 18432;
  float* bself   = f32blk + 18944;
  float* bz      = f32blk + 19456;
  u16*   bfblk   = (u16*)(ws + o_bfw);
  u16*   WgB     = bfblk + 0;
  u16*   WmB     = bfblk + 262144;
  u16*   WsB     = bfblk + 524288;
  u16*   WzB     = bfblk + 786432;
  u16*   geneB   = (u16*)(ws + o_geneB);
  u16*   AGGB    = geneB;
  u16*   Hb      = (u16*)(ws + o_Hb);
  u16*   Mb      = (u16*)(ws + o_Mb);
  float* sq      = ws + o_sq;
  float* deg     = ws + o_deg;
  float* dis     = ws + o_dis;
  int*   cnt     = (int*)(ws + o_cnt);
  int*   rs      = (int*)(ws + o_rs);
  int*   cur     = (int*)(ws + o_cur);
  int*   eidx    = (int*)(ws + o_eidx);
  float* ew      = ws + o_ew;
  int*   ccol    = (int*)(ws + o_ccol);
  float* cw      = ws + o_cw;
  float4* pts    = (float4*)(ws + o_pts);
  int*   gstart  = (int*)(ws + o_gsta);
  int*   gcur    = (int*)(ws + o_gcur);

  InPtrs ip;
  for (int s = 0; s < 12; ++s) ip.p[s] = d_in[s];

  k_conv_small<<<512, 256, 0, stream>>>(ip, flag, f32blk, bfblk, deg, cnt, sq);
  k_conv_gene<<<2048, 256, 0, stream>>>(d_in[0], d_in[1], (u32*)geneB);
  k_grid_scan<<<1, 1024, 0, stream>>>(coordsF, gstart, gcur);
  k_grid_fill<<<NN / 256, 256, 0, stream>>>(coordsF, sq, gcur, pts);
  k_knn_grid<<<NN / 4, 256, 0, stream>>>(pts, gstart, coordsF, sq, eidx, ew);
  k_degcnt<<<(NEDGE + 255) / 256, 256, 0, stream>>>(eidx, ew, deg, cnt);
  k_scan<<<1, 1024, 0, stream>>>(cnt, deg, rs, cur, dis);
  k_fill<<<(NEDGE + 255) / 256, 256, 0, stream>>>(eidx, ew, cur, ccol, cw);

  dim3 blk(256);
  k_mgemm<0><<<dim3(64, 8), blk, 0, stream>>>(d_in[0], geneB, WgB, bg1, coordsF, Wc1f, bc1f, flag, Hb, 512);
  k_agg<<<NN, 256, 0, stream>>>(rs, ccol, cw, dis, Hb, AGGB);
  k_mgemm23<<<dim3(64, 8), blk, 0, stream>>>(AGGB, WmB, bmsg, Hb, WsB, bself, Mb);
  k_mgemm<3><<<dim3(64, 1), blk, 0, stream>>>(nullptr, Mb, WzB, bz, nullptr, nullptr, nullptr, flag, d_out, 64);
}

// Round 20
// 299.964 us; speedup vs baseline: 1.0262x; 1.0262x over previous
//
#include <hip/hip_runtime.h>
#include <hip/hip_bf16.h>
#include <stdint.h>

#define NN 8192
#define GG 512
#define HH 512
#define LL 64
#define TOPK 9                 // K+1 = 9 (incl. self, self weight zeroed)
#define NEDGE (NN*TOPK)        // 73728 directed edges
#define NNZ (2*NEDGE)          // 147456 CSR entries after symmetrization
#define GRES 32                // spatial grid resolution (cell = 1/32)
#define NCELL (GRES*GRES)
#define LPAD 68                // LDS row pad: 34 dwords == 2 mod 32

typedef unsigned long long u64;
typedef unsigned int u32;
typedef unsigned short u16;

using bf16x8 = __attribute__((ext_vector_type(8))) short;
using f32x4  = __attribute__((ext_vector_type(4))) float;

struct InPtrs { const void* p[12]; };

__device__ __forceinline__ float bf2f(u16 u) { return __uint_as_float(((u32)u) << 16); }
__device__ __forceinline__ u16 f2bf(float f) {
  u32 x = __float_as_uint(f);
  u32 r = x + 0x7fffu + ((x >> 16) & 1u);   // RNE
  return (u16)(r >> 16);
}

// ---------------- inline dtype detection (wave 0 samples 64 u16s of coords) ----------------
__device__ __forceinline__ int detect_isbf(const void* coords_raw, int tid, int* sh) {
  if (tid < 64) {
    float v = bf2f(((const u16*)coords_raw)[tid]);
    bool bad = !(v >= -0.01f && v <= 1.02f);
    u64 bb = __ballot(bad);
    if (tid == 0) *sh = (bb == 0ULL) ? 1 : 0;
  }
  __syncthreads();
  return *sh;
}

// ---------------- convert small tensors + flag + zero deg/cnt + sq (from raw coords) ----------------
__global__ void k_conv_small(InPtrs in, int* __restrict__ flag,
                             float* __restrict__ f32blk, u16* __restrict__ bfblk,
                             float* __restrict__ deg, int* __restrict__ cnt,
                             float* __restrict__ sq) {
  __shared__ int sh;
  const int cnts[11] = {16384, 262144, 512, 1024, 512, 262144, 512, 262144, 512, 32768, 64};
  const int kind[11] = {0, 1, 0, 0, 0, 1, 0, 1, 0, 1, 0};
  const int doff[11] = {0, 0, 16384, 16896, 17920, 262144, 18432, 524288, 18944, 786432, 19456};
  const int TOTAL = 838720;
  int tid = threadIdx.x;
  int isbf = detect_isbf(in.p[1], tid, &sh);
  int gtid = blockIdx.x * blockDim.x + tid;
  if (gtid == 0) *flag = isbf;
  if (gtid < NN) {
    deg[gtid] = 0.0f;
    float x, y;
    if (isbf) { x = bf2f(((const u16*)in.p[1])[2 * gtid]); y = bf2f(((const u16*)in.p[1])[2 * gtid + 1]); }
    else      { x = ((const float*)in.p[1])[2 * gtid];     y = ((const float*)in.p[1])[2 * gtid + 1]; }
    sq[gtid] = __fadd_rn(__fmul_rn(x, x), __fmul_rn(y, y));
  } else if (gtid < 2 * NN) {
    cnt[gtid - NN] = 0;
  }
  for (int e = gtid; e < TOTAL; e += gridDim.x * blockDim.x) {
    int base = 0;
#pragma unroll
    for (int s = 0; s < 11; ++s) {
      if (e < base + cnts[s]) {
        int loc = e - base;
        const void* src = in.p[s + 1];
        float fv = isbf ? bf2f(((const u16*)src)[loc]) : ((const float*)src)[loc];
        if (kind[s] == 0) f32blk[doff[s] + loc] = fv;
        else bfblk[doff[s] + loc] = isbf ? ((const u16*)src)[loc] : f2bf(fv);
        break;
      }
      base += cnts[s];
    }
  }
}

// ---------------- gene -> bf16 ONLY in the fp32-input world ----------------
__global__ void k_conv_gene(const void* __restrict__ src, const void* __restrict__ coords_raw,
                            u32* __restrict__ geneB) {
  __shared__ int sh;
  const int TOTAL = NN * GG / 2;
  int isbf = detect_isbf(coords_raw, threadIdx.x, &sh);
  if (isbf) return;
  for (int e = blockIdx.x * blockDim.x + threadIdx.x; e < TOTAL; e += gridDim.x * blockDim.x) {
    float2 f = ((const float2*)src)[e];
    geneB[e] = (u32)f2bf(f.x) | ((u32)f2bf(f.y) << 16);
  }
}

__device__ __forceinline__ int cell_of(float v) {
  int c = (int)(v * (float)GRES);
  return c < 0 ? 0 : (c > GRES - 1 ? GRES - 1 : c);
}

// ---------------- grid histogram + scan (single block, LDS histogram) ----------------
__global__ __launch_bounds__(1024) void k_grid_scan(const float* __restrict__ coords,
                                                    int* __restrict__ gstart, int* __restrict__ gcur) {
  __shared__ int hist[NCELL];
  int t = threadIdx.x;
  hist[t] = 0;
  __syncthreads();
#pragma unroll
  for (int q = 0; q < 8; ++q) {
    int i = t + 1024 * q;
    int cx = cell_of(coords[2 * i]), cy = cell_of(coords[2 * i + 1]);
    atomicAdd(&hist[cy * GRES + cx], 1);
  }
  __syncthreads();
  int v = hist[t];
  __syncthreads();
  __shared__ int part[NCELL];
  part[t] = v;
  __syncthreads();
  for (int o = 1; o < NCELL; o <<= 1) {
    int add = 0;
    if (t >= o) add = part[t - o];
    __syncthreads();
    part[t] += add;
    __syncthreads();
  }
  int excl = part[t] - v;
  gstart[t] = excl;
  gcur[t] = excl;
  if (t == NCELL - 1) gstart[NCELL] = part[t];
}

__global__ void k_grid_fill(const float* __restrict__ coords, const float* __restrict__ sq,
                            int* __restrict__ gcur, float4* __restrict__ pts) {
  int i = blockIdx.x * blockDim.x + threadIdx.x;
  if (i < NN) {
    float x = coords[2*i], y = coords[2*i+1];
    int cx = cell_of(x), cy = cell_of(y);
    int p = atomicAdd(&gcur[cy * GRES + cx], 1);
    pts[p] = make_float4(x, y, sq[i], __int_as_float(i));
  }
}

// ---------------- KNN top-9 via spatial grid (exact; inline full-scan fallback) ----------------
__global__ __launch_bounds__(256) void k_knn_grid(const float4* __restrict__ pts,
                                                  const int* __restrict__ gstart,
                                                  const float* __restrict__ coords,
                                                  const float* __restrict__ sq,
                                                  int* __restrict__ eidx, float* __restrict__ ew) {
  const int w = threadIdx.x >> 6, lane = threadIdx.x & 63;
  const int i = blockIdx.x * 4 + w;
  const float qx = coords[2*i], qy = coords[2*i+1];
  const float sqi = sq[i];
  const int cx = cell_of(qx), cy = cell_of(qy);
  const int x0 = max(cx - 2, 0), x1 = min(cx + 2, GRES - 1);
  const int y0 = max(cy - 2, 0), y1 = min(cy + 2, GRES - 1);

  u64 a0 = ~0ULL, a1 = ~0ULL, a2 = ~0ULL, a3 = ~0ULL, a4 = ~0ULL,
      a5 = ~0ULL, a6 = ~0ULL, a7 = ~0ULL, a8 = ~0ULL;

#define KSTEP(A) { u64 t_ = A; bool p_ = x < t_; A = p_ ? x : t_; x = p_ ? t_ : x; }
  for (int yy = y0; yy <= y1; ++yy) {
    int sbeg = gstart[yy * GRES + x0];
    int send = gstart[yy * GRES + x1 + 1];
    for (int p = sbeg + lane; p < send; p += 64) {
      float4 pt = pts[p];
      float dot = __fmaf_rn(qy, pt.y, __fmul_rn(qx, pt.x));
      float d2  = __fsub_rn(__fadd_rn(sqi, pt.z), __fmul_rn(2.0f, dot));
      float d   = __fsqrt_rn(fmaxf(d2, 0.0f));
      u64 x = ((u64)__float_as_uint(d) << 32) | (u32)__float_as_int(pt.w);
      KSTEP(a0) KSTEP(a1) KSTEP(a2) KSTEP(a3) KSTEP(a4)
      KSTEP(a5) KSTEP(a6) KSTEP(a7) KSTEP(a8)
    }
  }

  u64 g9 = ~0ULL;
  for (int r = 0; r < TOPK; ++r) {
    u64 g = a0;
#pragma unroll
    for (int o = 32; o > 0; o >>= 1) {
      u64 other = __shfl_xor(g, o, 64);
      if (other < g) g = other;
    }
    bool own = (a0 == g);
    a0 = own ? a1 : a0;  a1 = own ? a2 : a1;  a2 = own ? a3 : a2;
    a3 = own ? a4 : a3;  a4 = own ? a5 : a4;  a5 = own ? a6 : a5;
    a6 = own ? a7 : a6;  a7 = own ? a8 : a7;  a8 = own ? ~0ULL : a8;
    g9 = g;
    if (lane == 0) {
      u32 dbits = (u32)(g >> 32);
      int j = (int)(g & 0xffffffffu);
      float d = __uint_as_float(dbits);
      float wgt = (j == i) ? 0.0f : expf(__fdiv_rn(-__fmul_rn(d, d), 2.0f));
      eidx[i * TOPK + r] = j;
      ew[i * TOPK + r] = wgt;
    }
  }

  float d9 = __uint_as_float((u32)(g9 >> 32));
  if (!(d9 < 0.0624f)) {
    a0 = a1 = a2 = a3 = a4 = a5 = a6 = a7 = a8 = ~0ULL;
    const float2* c2 = (const float2*)coords;
    for (int c = 0; c < 128; ++c) {
      int j = c * 64 + lane;
      float2 cjf = c2[j];
      float dot = __fmaf_rn(qy, cjf.y, __fmul_rn(qx, cjf.x));
      float d2  = __fsub_rn(__fadd_rn(sqi, sq[j]), __fmul_rn(2.0f, dot));
      float d   = __fsqrt_rn(fmaxf(d2, 0.0f));
      u64 x = ((u64)__float_as_uint(d) << 32) | (u32)j;
      KSTEP(a0) KSTEP(a1) KSTEP(a2) KSTEP(a3) KSTEP(a4)
      KSTEP(a5) KSTEP(a6) KSTEP(a7) KSTEP(a8)
    }
    for (int r = 0; r < TOPK; ++r) {
      u64 g = a0;
#pragma unroll
      for (int o = 32; o > 0; o >>= 1) {
        u64 other = __shfl_xor(g, o, 64);
        if (other < g) g = other;
      }
      bool own = (a0 == g);
      a0 = own ? a1 : a0;  a1 = own ? a2 : a1;  a2 = own ? a3 : a2;
      a3 = own ? a4 : a3;  a4 = own ? a5 : a4;  a5 = own ? a6 : a5;
      a6 = own ? a7 : a6;  a7 = own ? a8 : a7;  a8 = own ? ~0ULL : a8;
      if (lane == 0) {
        u32 dbits = (u32)(g >> 32);
        int j = (int)(g & 0xffffffffu);
        float d = __uint_as_float(dbits);
        float wgt = (j == i) ? 0.0f : expf(__fdiv_rn(-__fmul_rn(d, d), 2.0f));
        eidx[i * TOPK + r] = j;
        ew[i * TOPK + r] = wgt;
      }
    }
  }
#undef KSTEP
}

// ---------------- fused degree + count ----------------
__global__ void k_degcnt(const int* __restrict__ eidx, const float* __restrict__ ew,
                         float* __restrict__ deg, int* __restrict__ cnt) {
  int t = blockIdx.x * blockDim.x + threadIdx.x;
  if (t >= NEDGE) return;
  int i = t / TOPK;
  int j = eidx[t] & (NN - 1);
  float h = 0.5f * ew[t];
  atomicAdd(&deg[i], h);
  atomicAdd(&deg[j], h);
  atomicAdd(&cnt[i], 1);
  atomicAdd(&cnt[j], 1);
}

// ---------------- CSR scan (+ dis from deg) ----------------
__global__ __launch_bounds__(1024) void k_scan(const int* __restrict__ cnt,
                                               const float* __restrict__ deg,
                                               int* __restrict__ rs, int* __restrict__ cur,
                                               float* __restrict__ dis) {
  __shared__ int part[1024];
  int t = threadIdx.x;
  int base = t * 8;
  int loc[8]; int s = 0;
#pragma unroll
  for (int q = 0; q < 8; ++q) { loc[q] = s; s += cnt[base + q]; }
  part[t] = s;
  __syncthreads();
  for (int o = 1; o < 1024; o <<= 1) {
    int v = 0;
    if (t >= o) v = part[t - o];
    __syncthreads();
    part[t] += v;
    __syncthreads();
  }
  int excl = (t == 0) ? 0 : part[t - 1];
#pragma unroll
  for (int q = 0; q < 8; ++q) {
    int val = excl + loc[q];
    rs[base + q] = val;
    cur[base + q] = val;
    dis[base + q] = 1.0f / sqrtf(deg[base + q] + 1e-8f);
  }
  if (t == 1023) rs[NN] = excl + s;
}

__global__ void k_fill(const int* __restrict__ eidx, const float* __restrict__ ew,
                       int* __restrict__ cur, int* __restrict__ ccol, float* __restrict__ cw) {
  int t = blockIdx.x * blockDim.x + threadIdx.x;
  if (t >= NEDGE) return;
  int i = t / TOPK;
  int j = eidx[t] & (NN - 1);
  float h = 0.5f * ew[t];
  int s1 = atomicAdd(&cur[i], 1); ccol[s1] = j; cw[s1] = h;
  int s2 = atomicAdd(&cur[j], 1); ccol[s2] = i; cw[s2] = h;
}

// ---------------- agg = A_norm @ h (bf16 in/out; packed u32 stores) ----------------
__global__ __launch_bounds__(256) void k_agg(const int* __restrict__ rs, const int* __restrict__ ccol,
                                             const float* __restrict__ cw, const float* __restrict__ dis,
                                             const u16* __restrict__ h, u16* __restrict__ agg) {
  int i = blockIdx.x, t = threadIdx.x;
  int b = rs[i], e = rs[i + 1];
  float di = dis[i];
  float s0 = 0.f, s1 = 0.f;
  for (int q = b; q < e; ++q) {
    int c = ccol[q];
    float w = cw[q] * dis[c];
    u32 p = *(const u32*)(h + (size_t)c * HH + 2 * t);
    s0 = fmaf(w, bf2f((u16)(p & 0xffff)), s0);
    s1 = fmaf(w, bf2f((u16)(p >> 16)), s1);
  }
  u32 packed = (u32)f2bf(di * s0) | ((u32)f2bf(di * s1) << 16);
  *(u32*)(agg + (size_t)i * HH + 2 * t) = packed;
}

// ---------------- MFMA bf16 GEMM, BM=128: C = A[M,512]*W[C,512]^T ----------------
template <int MODE>
__global__ __launch_bounds__(256) void k_mgemm(const void* __restrict__ Araw, const u16* __restrict__ Aconv,
                                               const u16* __restrict__ W,
                                               const float* __restrict__ bias,
                                               const float* __restrict__ coords,
                                               const float* __restrict__ Wc1, const float* __restrict__ bc1,
                                               const int* __restrict__ flag,
                                               void* __restrict__ outp, int ldc) {
  __shared__ u16 As[128][LPAD];
  __shared__ u16 Bs[64][LPAD];
  const int tid = threadIdx.x, lane = tid & 63, w = tid >> 6;
  const int quad = lane >> 4, l16 = lane & 15;
  const int row0 = blockIdx.x * 128, col0 = blockIdx.y * 64;

  int flg = *flag;
  const u16* A = (MODE == 0) ? ((flg ? (const u16*)Araw : Aconv)) : Aconv;

  f32x4 acc[2][4];
#pragma unroll
  for (int mr = 0; mr < 2; ++mr)
#pragma unroll
    for (int n = 0; n < 4; ++n) acc[mr][n] = (f32x4){0.f, 0.f, 0.f, 0.f};

  const int r_ld = tid >> 3, c8_ld = (tid & 7) * 8;

  for (int kk = 0; kk < 512; kk += 64) {
    uint4 av[4]; uint4 bv[2];
#pragma unroll
    for (int q = 0; q < 4; ++q)
      av[q] = *(const uint4*)(A + (size_t)(row0 + r_ld + 32 * q) * 512 + kk + c8_ld);
#pragma unroll
    for (int q = 0; q < 2; ++q)
      bv[q] = *(const uint4*)(W + (size_t)(col0 + r_ld + 32 * q) * 512 + kk + c8_ld);
    __syncthreads();
#pragma unroll
    for (int q = 0; q < 4; ++q)
      *(uint4*)(&As[r_ld + 32 * q][c8_ld]) = av[q];
#pragma unroll
    for (int q = 0; q < 2; ++q)
      *(uint4*)(&Bs[r_ld + 32 * q][c8_ld]) = bv[q];
    __syncthreads();
#pragma unroll
    for (int kc = 0; kc < 2; ++kc) {
      bf16x8 af[2], bfr[4];
#pragma unroll
      for (int mr = 0; mr < 2; ++mr)
        af[mr] = *(const bf16x8*)(&As[w * 32 + mr * 16 + l16][kc * 32 + quad * 8]);
#pragma unroll
      for (int n = 0; n < 4; ++n)
        bfr[n] = *(const bf16x8*)(&Bs[n * 16 + l16][kc * 32 + quad * 8]);
#pragma unroll
      for (int mr = 0; mr < 2; ++mr)
#pragma unroll
        for (int n = 0; n < 4; ++n)
          acc[mr][n] = __builtin_amdgcn_mfma_f32_16x16x32_bf16(af[mr], bfr[n], acc[mr][n], 0, 0, 0);
    }
  }

#pragma unroll
  for (int mr = 0; mr < 2; ++mr) {
    int rbase = row0 + w * 32 + mr * 16 + quad * 4;
    float cx[4], cy[4];
    if (MODE == 0) {
#pragma unroll
      for (int reg = 0; reg < 4; ++reg) { cx[reg] = coords[2 * (rbase + reg)]; cy[reg] = coords[2 * (rbase + reg) + 1]; }
    }
#pragma unroll
    for (int n = 0; n < 4; ++n) {
      int cg = col0 + n * 16 + l16;
      float bval = bias[cg];
      float wc0 = 0.f, wc1 = 0.f, bcv = 0.f;
      if (MODE == 0) { wc0 = Wc1[2 * cg]; wc1 = Wc1[2 * cg + 1]; bcv = bc1[cg]; }
#pragma unroll
      for (int reg = 0; reg < 4; ++reg) {
        int rg = rbase + reg;
        float v = acc[mr][n][reg] + bval;
        if (MODE == 0) {
          float hc = cx[reg] * wc0 + cy[reg] * wc1 + bcv;
          v = fmaxf(v, 0.f) + fmaxf(hc, 0.f);
          ((u16*)outp)[(size_t)rg * ldc + cg] = f2bf(v);
        } else {
          if (flg) ((u16*)outp)[(size_t)rg * ldc + cg] = f2bf(v);
          else     ((float*)outp)[(size_t)rg * ldc + cg] = v;
        }
      }
    }
  }
}

// ---------------- FUSED GEMM2+3 (dual-stream, BM=128, 2 blocks/CU cap) ----------------
// Bs over-sized to [80] rows: LDS 79.5 KB forces 2 blocks/CU — measured dose-response:
// 2/CU=77MB writes/57µs, 3/CU=168MB/72µs, 4/CU=215MB/91µs.
__global__ __launch_bounds__(256) void k_mgemm23(const u16* __restrict__ A1, const u16* __restrict__ W1,
                                                 const float* __restrict__ b1,
                                                 const u16* __restrict__ A2, const u16* __restrict__ W2,
                                                 const float* __restrict__ b2,
                                                 u16* __restrict__ outp) {
  __shared__ u16 As1[128][LPAD];
  __shared__ u16 As2[128][LPAD];
  __shared__ u16 Bs1[80][LPAD];   // rows 0..63 used; extra rows cap occupancy at 2 blocks/CU
  __shared__ u16 Bs2[80][LPAD];
  const int tid = threadIdx.x, lane = tid & 63, w = tid >> 6;
  const int quad = lane >> 4, l16 = lane & 15;
  const int row0 = blockIdx.x * 128, col0 = blockIdx.y * 64;

  f32x4 acc1[2][4], acc2[2][4];
#pragma unroll
  for (int mr = 0; mr < 2; ++mr)
#pragma unroll
    for (int n = 0; n < 4; ++n) {
      acc1[mr][n] = (f32x4){0.f, 0.f, 0.f, 0.f};
      acc2[mr][n] = (f32x4){0.f, 0.f, 0.f, 0.f};
    }

  const int r_ld = tid >> 3, c8_ld = (tid & 7) * 8;

  for (int kk = 0; kk < 512; kk += 64) {
    uint4 av1[4], av2[4], bv1[2], bv2[2];
#pragma unroll
    for (int q = 0; q < 4; ++q) {
      av1[q] = *(const uint4*)(A1 + (size_t)(row0 + r_ld + 32 * q) * 512 + kk + c8_ld);
      av2[q] = *(const uint4*)(A2 + (size_t)(row0 + r_ld + 32 * q) * 512 + kk + c8_ld);
    }
#pragma unroll
    for (int q = 0; q < 2; ++q) {
      bv1[q] = *(const uint4*)(W1 + (size_t)(col0 + r_ld + 32 * q) * 512 + kk + c8_ld);
      bv2[q] = *(const uint4*)(W2 + (size_t)(col0 + r_ld + 32 * q) * 512 + kk + c8_ld);
    }
    __syncthreads();
#pragma unroll
    for (int q = 0; q < 4; ++q) {
      *(uint4*)(&As1[r_ld + 32 * q][c8_ld]) = av1[q];
      *(uint4*)(&As2[r_ld + 32 * q][c8_ld]) = av2[q];
    }
#pragma unroll
    for (int q = 0; q < 2; ++q) {
      *(uint4*)(&Bs1[r_ld + 32 * q][c8_ld]) = bv1[q];
      *(uint4*)(&Bs2[r_ld + 32 * q][c8_ld]) = bv2[q];
    }
    __syncthreads();
#pragma unroll
    for (int kc = 0; kc < 2; ++kc) {
      bf16x8 af1[2], af2[2], bf1[4], bf2[4];
#pragma unroll
      for (int mr = 0; mr < 2; ++mr) {
        af1[mr] = *(const bf16x8*)(&As1[w * 32 + mr * 16 + l16][kc * 32 + quad * 8]);
        af2[mr] = *(const bf16x8*)(&As2[w * 32 + mr * 16 + l16][kc * 32 + quad * 8]);
      }
#pragma unroll
      for (int n = 0; n < 4; ++n) {
        bf1[n] = *(const bf16x8*)(&Bs1[n * 16 + l16][kc * 32 + quad * 8]);
        bf2[n] = *(const bf16x8*)(&Bs2[n * 16 + l16][kc * 32 + quad * 8]);
      }
#pragma unroll
      for (int mr = 0; mr < 2; ++mr)
#pragma unroll
        for (int n = 0; n < 4; ++n) {
          acc1[mr][n] = __builtin_amdgcn_mfma_f32_16x16x32_bf16(af1[mr], bf1[n], acc1[mr][n], 0, 0, 0);
          acc2[mr][n] = __builtin_amdgcn_mfma_f32_16x16x32_bf16(af2[mr], bf2[n], acc2[mr][n], 0, 0, 0);
        }
    }
  }

#pragma unroll
  for (int mr = 0; mr < 2; ++mr) {
    int rbase = row0 + w * 32 + mr * 16 + quad * 4;
#pragma unroll
    for (int n = 0; n < 4; ++n) {
      int cg = col0 + n * 16 + l16;
      float bv1 = b1[cg], bv2 = b2[cg];
#pragma unroll
      for (int reg = 0; reg < 4; ++reg) {
        int rg = rbase + reg;
        float msg  = fmaxf(acc1[mr][n][reg] + bv1, 0.f);
        float self = fmaxf(acc2[mr][n][reg] + bv2, 0.f);
        outp[(size_t)rg * 512 + cg] = f2bf(fmaxf(msg + self, 0.f));
      }
    }
  }
}

extern "C" void kernel_launch(void* const* d_in, const int* in_sizes, int n_in,
                              void* d_out, int out_size, void* d_ws, size_t ws_size,
                              hipStream_t stream) {
  float* ws = (float*)d_ws;
  size_t off = 0;
  auto alloc = [&](size_t n) { size_t o = off; off += (n + 15) & ~(size_t)15; return o; };

  const size_t PLANE = (size_t)NN * HH / 2;

  size_t o_flag  = alloc(16);
  size_t o_f32   = alloc(19520);
  size_t o_bfw   = alloc(409600);
  size_t o_geneB = alloc(PLANE);
  size_t o_Hb    = alloc(PLANE);
  size_t o_Mb    = alloc(PLANE);
  size_t o_sq    = alloc(NN);
  size_t o_deg   = alloc(NN);
  size_t o_dis   = alloc(NN);
  size_t o_cnt   = alloc(NN);
  size_t o_rs    = alloc(NN + 16);
  size_t o_cur   = alloc(NN);
  size_t o_eidx  = alloc(NEDGE);
  size_t o_ew    = alloc(NEDGE);
  size_t o_ccol  = alloc(NNZ);
  size_t o_cw    = alloc(NNZ);
  size_t o_pts   = alloc(NN * 4);
  size_t o_gsta  = alloc(NCELL + 16);
  size_t o_gcur  = alloc(NCELL);
  (void)ws_size;

  int*   flag    = (int*)(ws + o_flag);
  float* f32blk  = ws + o_f32;
  float* coordsF = f32blk + 0;
  float* bg1     = f32blk + 16384;
  float* Wc1f    = f32blk + 16896;
  float* bc1f    = f32blk + 17920;
  float* bmsg    = f32blk + 18432;
  float* bself   = f32blk + 18944;
  float* bz      = f32blk + 19456;
  u16*   bfblk   = (u16*)(ws + o_bfw);
  u16*   WgB     = bfblk + 0;
  u16*   WmB     = bfblk + 262144;
  u16*   WsB     = bfblk + 524288;
  u16*   WzB     = bfblk + 786432;
  u16*   geneB   = (u16*)(ws + o_geneB);
  u16*   AGGB    = geneB;
  u16*   Hb      = (u16*)(ws + o_Hb);
  u16*   Mb      = (u16*)(ws + o_Mb);
  float* sq      = ws + o_sq;
  float* deg     = ws + o_deg;
  float* dis     = ws + o_dis;
  int*   cnt     = (int*)(ws + o_cnt);
  int*   rs      = (int*)(ws + o_rs);
  int*   cur     = (int*)(ws + o_cur);
  int*   eidx    = (int*)(ws + o_eidx);
  float* ew      = ws + o_ew;
  int*   ccol    = (int*)(ws + o_ccol);
  float* cw      = ws + o_cw;
  float4* pts    = (float4*)(ws + o_pts);
  int*   gstart  = (int*)(ws + o_gsta);
  int*   gcur    = (int*)(ws + o_gcur);

  InPtrs ip;
  for (int s = 0; s < 12; ++s) ip.p[s] = d_in[s];

  k_conv_small<<<512, 256, 0, stream>>>(ip, flag, f32blk, bfblk, deg, cnt, sq);
  k_conv_gene<<<2048, 256, 0, stream>>>(d_in[0], d_in[1], (u32*)geneB);
  k_grid_scan<<<1, 1024, 0, stream>>>(coordsF, gstart, gcur);
  k_grid_fill<<<NN / 256, 256, 0, stream>>>(coordsF, sq, gcur, pts);
  k_knn_grid<<<NN / 4, 256, 0, stream>>>(pts, gstart, coordsF, sq, eidx, ew);
  k_degcnt<<<(NEDGE + 255) / 256, 256, 0, stream>>>(eidx, ew, deg, cnt);
  k_scan<<<1, 1024, 0, stream>>>(cnt, deg, rs, cur, dis);
  k_fill<<<(NEDGE + 255) / 256, 256, 0, stream>>>(eidx, ew, cur, ccol, cw);

  dim3 blk(256);
  k_mgemm<0><<<dim3(64, 8), blk, 0, stream>>>(d_in[0], geneB, WgB, bg1, coordsF, Wc1f, bc1f, flag, Hb, 512);
  k_agg<<<NN, 256, 0, stream>>>(rs, ccol, cw, dis, Hb, AGGB);
  k_mgemm23<<<dim3(64, 8), blk, 0, stream>>>(AGGB, WmB, bmsg, Hb, WsB, bself, Mb);
  k_mgemm<3><<<dim3(64, 1), blk, 0, stream>>>(nullptr, Mb, WzB, bz, nullptr, nullptr, nullptr, flag, d_out, 64);
}